// Round 16
// baseline (646.608 us; speedup 1.0000x reference)
//
#include <hip/hip_runtime.h>
#include <hip/hip_bf16.h>

#define MUL_Sc 256
#define DIM_Hc 640
#define IN_COLS 644
#define KF 768
#define NTS 32

#define C0F 0.05103103630798287f
#define INV_SQRT3F 0.57735026918962576f

typedef __attribute__((ext_vector_type(8))) short short8;
typedef __attribute__((ext_vector_type(4))) float f32x4;

#define MFMA(a, b, c) __builtin_amdgcn_mfma_f32_16x16x32_bf16((a), (b), (c), 0, 0, 0)

__device__ __forceinline__ unsigned short f2bf(float x) {
    union { float f; unsigned u; } v; v.f = x;
    unsigned r = v.u + 0x7fffu + ((v.u >> 16) & 1u);   // RNE
    return (unsigned short)(r >> 16);
}

// async global -> LDS, 16B/lane, aux=2 (NT: don't pollute L2 with single-use stream)
__device__ __forceinline__ void gload_lds16_nt(const unsigned short* g, unsigned short* l) {
    __builtin_amdgcn_global_load_lds((const __attribute__((address_space(1))) void*)g,
                                     (__attribute__((address_space(3))) void*)l, 16, 0, 2);
}

// ---- weight prep: fp32 [k][col] -> bf16 transposed [col][k] (cacheable - we WANT these in L2) ----
__global__ void prep_weights(const float* __restrict__ Wss, const float* __restrict__ Wvv,
                             const float* __restrict__ Wssg, const float* __restrict__ Wvvg,
                             const float* __restrict__ Wsv, const float* __restrict__ Wvs,
                             unsigned short* __restrict__ wt) {
    int i = blockIdx.x * 256 + threadIdx.x;
    const int N_SG = 384 * 384;
    const int N_SV = 128 * 256;
    const int N_VS = 128 * 128;
    if (i < N_SG) {
        int col = i / 384, k = i % 384;
        float v;
        if (col < 256) v = (k < 256) ? Wss[k * 256 + col] : Wvv[(k - 256) * 256 + col];
        else { int c = col - 256; v = (k < 256) ? Wssg[k * 128 + c] : Wvvg[(k - 256) * 128 + c]; }
        wt[i] = f2bf(v);
    } else if (i < N_SG + N_SV) {
        int j = i - N_SG; int col = j >> 8, k = j & 255;
        wt[i] = f2bf(Wsv[k * 128 + col]);
    } else if (i < N_SG + N_SV + N_VS) {
        int j = i - N_SG - N_SV; int col = j >> 7, k = j & 127;
        wt[i] = f2bf(Wvs[k * 128 + col]);
    }
}

// ==== kernel 1: din -> pre-swizzled bf16 feature tiles + psv; ALL traffic non-temporal ====
__global__ __launch_bounds__(512, 2)
void convert_feat(const float* __restrict__ din, unsigned short* __restrict__ featg,
                  float* __restrict__ psvg, int N) {
    const int T = blockIdx.x;
    const int tid = threadIdx.x;
    const int g = tid >> 4;
    const int j = tid & 15;
    int n = T * NTS + g; if (n >= N) n = N - 1;
    const float* row = din + (size_t)n * IN_COLS;
    float ps  = row[DIM_Hc];
    float pv0 = row[DIM_Hc + 1], pv1 = row[DIM_Hc + 2], pv2 = row[DIM_Hc + 3];
    if (j == 0 && T * NTS + g < N) {
        f32x4 pp; pp[0] = ps; pp[1] = pv0; pp[2] = pv1; pp[3] = pv2;
        __builtin_nontemporal_store(pp, (f32x4*)(psvg + 4 * (size_t)(T * NTS + g)));
    }
    char* fb = (char*)featg + (size_t)T * (NTS * KF * 2);
    const int swz  = (g & 7) << 4;
    const int rowb = g * (KF * 2);
    {
        int c = 16 * j;
        f32x4 x0 = __builtin_nontemporal_load((const f32x4*)(row + c));
        f32x4 x1 = __builtin_nontemporal_load((const f32x4*)(row + c + 4));
        f32x4 x2 = __builtin_nontemporal_load((const f32x4*)(row + c + 8));
        f32x4 x3 = __builtin_nontemporal_load((const f32x4*)(row + c + 12));
        short8 p0, p1;
        p0[0]=(short)f2bf(x0[0]); p0[1]=(short)f2bf(x0[1]); p0[2]=(short)f2bf(x0[2]); p0[3]=(short)f2bf(x0[3]);
        p0[4]=(short)f2bf(x1[0]); p0[5]=(short)f2bf(x1[1]); p0[6]=(short)f2bf(x1[2]); p0[7]=(short)f2bf(x1[3]);
        p1[0]=(short)f2bf(x2[0]); p1[1]=(short)f2bf(x2[1]); p1[2]=(short)f2bf(x2[2]); p1[3]=(short)f2bf(x2[3]);
        p1[4]=(short)f2bf(x3[0]); p1[5]=(short)f2bf(x3[1]); p1[6]=(short)f2bf(x3[2]); p1[7]=(short)f2bf(x3[3]);
        __builtin_nontemporal_store(p0, (short8*)(fb + ((rowb + c * 2) ^ swz)));
        __builtin_nontemporal_store(p1, (short8*)(fb + ((rowb + (c + 8) * 2) ^ swz)));
    }
    {
        int u0 = 8 * j;
        const float* p = row + MUL_Sc + 3 * u0;
        float e[24];
        #pragma unroll
        for (int q = 0; q < 6; ++q) {
            f32x4 v = __builtin_nontemporal_load((const f32x4*)(p + 4 * q));
            e[4*q+0] = v[0]; e[4*q+1] = v[1]; e[4*q+2] = v[2]; e[4*q+3] = v[3];
        }
        short8 dp, k0, k1, k2;
        #pragma unroll
        for (int m = 0; m < 8; ++m) {
            float a = e[3*m], b = e[3*m+1], c = e[3*m+2];
            dp[m] = (short)f2bf((a * pv0 + b * pv1 + c * pv2) * INV_SQRT3F);
            k0[m] = (short)f2bf(a);
            k1[m] = (short)f2bf(b);
            k2[m] = (short)f2bf(c);
        }
        __builtin_nontemporal_store(dp, (short8*)(fb + ((rowb + (256 + u0) * 2) ^ swz)));
        __builtin_nontemporal_store(k0, (short8*)(fb + ((rowb + (384 + u0) * 2) ^ swz)));
        __builtin_nontemporal_store(k1, (short8*)(fb + ((rowb + (512 + u0) * 2) ^ swz)));
        __builtin_nontemporal_store(k2, (short8*)(fb + ((rowb + (640 + u0) * 2) ^ swz)));
    }
}

// ==== kernel 2: NT-DMA feat -> LDS, compute (weights cacheable), NT coalesced stores ====
__global__ __launch_bounds__(512, 2)
void gemm_main(const unsigned short* __restrict__ featg, const float* __restrict__ psvg,
               const unsigned short* __restrict__ wt, const float* __restrict__ bias,
               float* __restrict__ out, int N) {
    __shared__ unsigned short feat[NTS * KF];   // 48 KB; reused as f32 bounce [16][644] in epilogue

    const int tid = threadIdx.x;
    const int T = blockIdx.x;
    const int n0 = T * NTS;

    // pure-DMA staging (non-temporal): 6 rounds x 512 threads x 16B = 48KB
    {
        const unsigned short* gb = featg + (size_t)T * (NTS * KF);
        unsigned short* lb = feat + (tid >> 6) * 512;
        #pragma unroll
        for (int r = 0; r < 6; ++r)
            gload_lds16_nt(gb + ((size_t)r * 512 + tid) * 8, lb + r * 4096);
    }
    __syncthreads();

    const int wave = tid >> 6;
    const int lane = tid & 63;
    const int l15  = lane & 15;
    const int lkb  = (lane >> 4) << 3;
    const int rbase = (lane >> 4) << 2;
    const char* fbr = (const char*)feat;
    const int swzr = (l15 & 7) << 4;

    const unsigned short* WTsg = wt;
    const unsigned short* WTsv = wt + 384 * 384;
    const unsigned short* WTvs = wt + 384 * 384 + 128 * 256;

    float bc0 = bias[(wave)     * 16 + l15];
    float bc1 = bias[(wave + 8) * 16 + l15];

    float pss[2][4];
    #pragma unroll
    for (int m = 0; m < 2; ++m)
    #pragma unroll
    for (int i = 0; i < 4; ++i) {
        int n = n0 + m * 16 + rbase + i;
        pss[m][i] = psvg[4 * (size_t)(n < N ? n : N - 1)];
    }

    // ---- sg GEMM: t=0,1 scal col-tiles, t=2 gate col-tile ----
    f32x4 accS[3][2];
    #pragma unroll
    for (int t = 0; t < 3; ++t) { accS[t][0] = (f32x4){0,0,0,0}; accS[t][1] = (f32x4){0,0,0,0}; }

    #pragma unroll
    for (int ks = 0; ks < 8; ++ks) {      // xs part K=256
        int kf = ks * 32 + lkb;
        short8 a0 = *(const short8*)(fbr + ((l15 * 1536 + kf * 2) ^ swzr));
        short8 a1 = *(const short8*)(fbr + (((16 + l15) * 1536 + kf * 2) ^ swzr));
        #pragma unroll
        for (int t = 0; t < 3; ++t) {
            int ct = wave + t * 8;
            short8 b = *(const short8*)(WTsg + (ct * 16 + l15) * 384 + ks * 32 + lkb);
            accS[t][0] = MFMA(a0, b, accS[t][0]);
            accS[t][1] = MFMA(a1, b, accS[t][1]);
        }
    }
    #pragma unroll
    for (int t = 0; t < 3; ++t)
    #pragma unroll
    for (int m = 0; m < 2; ++m)
    #pragma unroll
    for (int i = 0; i < 4; ++i) accS[t][m][i] *= pss[m][i];
    #pragma unroll
    for (int ks = 0; ks < 4; ++ks) {      // dot part K=128
        int kf = 256 + ks * 32 + lkb;
        short8 a0 = *(const short8*)(fbr + ((l15 * 1536 + kf * 2) ^ swzr));
        short8 a1 = *(const short8*)(fbr + (((16 + l15) * 1536 + kf * 2) ^ swzr));
        #pragma unroll
        for (int t = 0; t < 3; ++t) {
            int ct = wave + t * 8;
            short8 b = *(const short8*)(WTsg + (ct * 16 + l15) * 384 + 256 + ks * 32 + lkb);
            accS[t][0] = MFMA(a0, b, accS[t][0]);
            accS[t][1] = MFMA(a1, b, accS[t][1]);
        }
    }

    // gate -> sigmoid in registers (gate col wave*16+l15 == vec u-tile col)
    float sgr[2][4];
    #pragma unroll
    for (int m = 0; m < 2; ++m)
    #pragma unroll
    for (int i = 0; i < 4; ++i) sgr[m][i] = 1.f / (1.f + __expf(-C0F * accS[2][m][i]));

    // ---- vec GEMMs: a1 (xs, K=256) + v2_k (xv planes, K=128 x3) ----
    f32x4 accA[2], accV[3][2];
    accA[0] = (f32x4){0,0,0,0}; accA[1] = (f32x4){0,0,0,0};
    #pragma unroll
    for (int k = 0; k < 3; ++k) { accV[k][0] = (f32x4){0,0,0,0}; accV[k][1] = (f32x4){0,0,0,0}; }

    #pragma unroll
    for (int ks = 0; ks < 8; ++ks) {
        int kf = ks * 32 + lkb;
        short8 a0 = *(const short8*)(fbr + ((l15 * 1536 + kf * 2) ^ swzr));
        short8 a1 = *(const short8*)(fbr + (((16 + l15) * 1536 + kf * 2) ^ swzr));
        short8 b = *(const short8*)(WTsv + (wave * 16 + l15) * 256 + ks * 32 + lkb);
        accA[0] = MFMA(a0, b, accA[0]);
        accA[1] = MFMA(a1, b, accA[1]);
    }
    #pragma unroll
    for (int ks = 0; ks < 4; ++ks) {
        short8 b = *(const short8*)(WTvs + (wave * 16 + l15) * 128 + ks * 32 + lkb);
        #pragma unroll
        for (int p = 0; p < 3; ++p) {
            int kf = 384 + 128 * p + ks * 32 + lkb;
            short8 a0 = *(const short8*)(fbr + ((l15 * 1536 + kf * 2) ^ swzr));
            short8 a1 = *(const short8*)(fbr + (((16 + l15) * 1536 + kf * 2) ^ swzr));
            accV[p][0] = MFMA(a0, b, accV[p][0]);
            accV[p][1] = MFMA(a1, b, accV[p][1]);
        }
    }

    __syncthreads();   // all feat LDS reads done -> reuse feat as f32 bounce buffer

    // ==== epilogue: LDS bounce -> fully coalesced NON-TEMPORAL streaming stores ====
    float* ldso = (float*)feat;      // [16][644] floats
    const int u = wave * 16 + l15;
    #pragma unroll
    for (int m = 0; m < 2; ++m) {
        #pragma unroll
        for (int t = 0; t < 2; ++t) {
            int col = (wave + t * 8) * 16 + l15;
            float bc = t == 0 ? bc0 : bc1;
            #pragma unroll
            for (int i = 0; i < 4; ++i) {
                int r = rbase + i;
                float sc = C0F * accS[t][m][i] + bc;
                ldso[r * 644 + col] = sc / (1.f + __expf(-sc));
            }
        }
        #pragma unroll
        for (int i = 0; i < 4; ++i) {
            int r = rbase + i;
            int n = n0 + m * 16 + r;
            size_t pb = 4 * (size_t)(n < N ? n : N - 1);
            float ps  = pss[m][i];
            float pv0 = psvg[pb + 1], pv1 = psvg[pb + 2], pv2 = psvg[pb + 3];
            float sg  = sgr[m][i];
            float av  = accA[m][i];
            float* vb = ldso + r * 644 + MUL_Sc + 3 * u;
            vb[0] = C0F * (av * pv0 + accV[0][m][i] * ps) * sg;
            vb[1] = C0F * (av * pv1 + accV[1][m][i] * ps) * sg;
            vb[2] = C0F * (av * pv2 + accV[2][m][i] * ps) * sg;
        }
        __syncthreads();
        {
            int r  = tid >> 5;             // 0..15
            int c0 = (tid & 31) * 20;      // 0..620
            int n  = n0 + m * 16 + r;
            if (n < N) {
                const float* src = ldso + r * 644 + c0;
                float* dst = out + (size_t)n * DIM_Hc + c0;
                #pragma unroll
                for (int q = 0; q < 5; ++q)
                    __builtin_nontemporal_store(*(const f32x4*)(src + 4 * q), (f32x4*)(dst + 4 * q));
            }
        }
        __syncthreads();
    }
}

extern "C" void kernel_launch(void* const* d_in, const int* in_sizes, int n_in,
                              void* d_out, int out_size, void* d_ws, size_t ws_size,
                              hipStream_t stream) {
    const float* din  = (const float*)d_in[0];
    const float* Wss  = (const float*)d_in[1];
    const float* Wvv  = (const float*)d_in[2];
    const float* Wssg = (const float*)d_in[3];
    const float* Wvvg = (const float*)d_in[4];
    const float* Wsv  = (const float*)d_in[5];
    const float* Wvs  = (const float*)d_in[6];
    const float* bias = (const float*)d_in[7];
    float* out = (float*)d_out;
    unsigned short* wt = (unsigned short*)d_ws;

    const size_t WT_SHORTS = 384 * 384 + 128 * 256 + 128 * 128;
    const size_t WT_BYTES = WT_SHORTS * 2;
    if (ws_size < WT_BYTES) return;

    int N = in_sizes[0] / IN_COLS;
    int ntiles = (N + NTS - 1) / NTS;

    int prep_total = (int)WT_SHORTS;
    prep_weights<<<(prep_total + 255) / 256, 256, 0, stream>>>(Wss, Wvv, Wssg, Wvvg, Wsv, Wvs, wt);

    size_t feat_bytes = (size_t)ntiles * NTS * KF * 2;
    size_t psv_bytes  = (size_t)ntiles * NTS * 4 * sizeof(float);
    size_t need = WT_BYTES + feat_bytes + psv_bytes;
    if (ws_size < need) return;   // N=100000 -> ~156MB, expected to fit

    unsigned short* featg = wt + WT_SHORTS;
    float* psvg = (float*)((char*)d_ws + WT_BYTES + feat_bytes);
    convert_feat<<<ntiles, 512, 0, stream>>>(din, featg, psvg, N);
    gemm_main<<<ntiles, 512, 0, stream>>>(featg, psvg, wt, bias, out, N);
}

// Round 17
// 332.417 us; speedup vs baseline: 1.9452x; 1.9452x over previous
//
#include <hip/hip_runtime.h>
#include <hip/hip_bf16.h>

#define MUL_Sc 256
#define DIM_Hc 640
#define IN_COLS 644
#define KF 768
#define NT 64

#define C0F 0.05103103630798287f
#define INV_SQRT3F 0.57735026918962576f

typedef __attribute__((ext_vector_type(8))) short short8;
typedef __attribute__((ext_vector_type(4))) float f32x4;

#define MFMA(a, b, c) __builtin_amdgcn_mfma_f32_16x16x32_bf16((a), (b), (c), 0, 0, 0)

__device__ __forceinline__ unsigned short f2bf(float x) {
    union { float f; unsigned u; } v; v.f = x;
    unsigned r = v.u + 0x7fffu + ((v.u >> 16) & 1u);   // RNE
    return (unsigned short)(r >> 16);
}

// ---- diagnostic sink: ideal grid-stride float4 streaming writes ----
__global__ __launch_bounds__(256)
void sink_fill(float* __restrict__ dst, long long nvec4, int passes) {
    f32x4 v; v[0] = 1.f; v[1] = 2.f; v[2] = 3.f; v[3] = 4.f;
    for (int p = 0; p < passes; ++p) {
        for (long long i = (long long)blockIdx.x * blockDim.x + threadIdx.x;
             i < nvec4; i += (long long)gridDim.x * blockDim.x)
            ((f32x4*)dst)[i] = v;
    }
}

// ---- weight prep: fp32 [k][col] -> bf16 transposed [col][k] (proven numerics) ----
__global__ void prep_weights(const float* __restrict__ Wss, const float* __restrict__ Wvv,
                             const float* __restrict__ Wssg, const float* __restrict__ Wvvg,
                             const float* __restrict__ Wsv, const float* __restrict__ Wvs,
                             unsigned short* __restrict__ wt) {
    int i = blockIdx.x * 256 + threadIdx.x;
    const int N_SG = 384 * 384;
    const int N_SV = 128 * 256;
    const int N_VS = 128 * 128;
    if (i < N_SG) {
        int col = i / 384, k = i % 384;
        float v;
        if (col < 256) v = (k < 256) ? Wss[k * 256 + col] : Wvv[(k - 256) * 256 + col];
        else { int c = col - 256; v = (k < 256) ? Wssg[k * 128 + c] : Wvvg[(k - 256) * 128 + c]; }
        wt[i] = f2bf(v);
    } else if (i < N_SG + N_SV) {
        int j = i - N_SG; int col = j >> 8, k = j & 255;
        wt[i] = f2bf(Wsv[k * 128 + col]);
    } else if (i < N_SG + N_SV + N_VS) {
        int j = i - N_SG - N_SV; int col = j >> 7, k = j & 127;
        wt[i] = f2bf(Wvs[k * 128 + col]);
    }
}

// ---- R12 fused kernel (proven 234.5us): NT=64, single barrier, gate in registers ----
__global__ __launch_bounds__(512, 2)
void fused_main(const float* __restrict__ din, const unsigned short* __restrict__ wt,
                const float* __restrict__ bias, float* __restrict__ out, int N) {
    __shared__ unsigned short feat[NT * KF];   // 96 KB, XOR-swizzled: byte ^= (node&7)<<4
    __shared__ float psv[NT * 4];

    const int tid = threadIdx.x;
    const int n0 = blockIdx.x * NT;

    // ---------------- staging: 8 threads per node ----------------
    {
        const int g = tid >> 3;       // local node 0..63
        const int j = tid & 7;
        int n = n0 + g; if (n >= N) n = N - 1;
        const float* row = din + (size_t)n * IN_COLS;
        float ps  = row[DIM_Hc];
        float pv0 = row[DIM_Hc + 1], pv1 = row[DIM_Hc + 2], pv2 = row[DIM_Hc + 3];
        if (j == 0) { psv[g*4+0] = ps; psv[g*4+1] = pv0; psv[g*4+2] = pv1; psv[g*4+3] = pv2; }
        char* fb = (char*)feat;
        const int swz  = (g & 7) << 4;
        const int rowb = g * (KF * 2);

        #pragma unroll
        for (int half = 0; half < 2; ++half) {
            int c = 32 * j + 16 * half;
            float4 x0 = *(const float4*)(row + c);
            float4 x1 = *(const float4*)(row + c + 4);
            float4 x2 = *(const float4*)(row + c + 8);
            float4 x3 = *(const float4*)(row + c + 12);
            short8 p0, p1;
            p0[0]=(short)f2bf(x0.x); p0[1]=(short)f2bf(x0.y); p0[2]=(short)f2bf(x0.z); p0[3]=(short)f2bf(x0.w);
            p0[4]=(short)f2bf(x1.x); p0[5]=(short)f2bf(x1.y); p0[6]=(short)f2bf(x1.z); p0[7]=(short)f2bf(x1.w);
            p1[0]=(short)f2bf(x2.x); p1[1]=(short)f2bf(x2.y); p1[2]=(short)f2bf(x2.z); p1[3]=(short)f2bf(x2.w);
            p1[4]=(short)f2bf(x3.x); p1[5]=(short)f2bf(x3.y); p1[6]=(short)f2bf(x3.z); p1[7]=(short)f2bf(x3.w);
            *(short8*)(fb + ((rowb + c * 2) ^ swz))       = p0;
            *(short8*)(fb + ((rowb + (c + 8) * 2) ^ swz)) = p1;
        }
        #pragma unroll
        for (int half = 0; half < 2; ++half) {
            int u0 = 16 * j + 8 * half;
            const float* p = row + MUL_Sc + 3 * u0;
            float e[24];
            #pragma unroll
            for (int q = 0; q < 6; ++q) {
                float4 v = *(const float4*)(p + 4 * q);
                e[4*q+0] = v.x; e[4*q+1] = v.y; e[4*q+2] = v.z; e[4*q+3] = v.w;
            }
            short8 dp, k0, k1, k2;
            #pragma unroll
            for (int m = 0; m < 8; ++m) {
                float a = e[3*m], b = e[3*m+1], c = e[3*m+2];
                dp[m] = (short)f2bf((a * pv0 + b * pv1 + c * pv2) * INV_SQRT3F);
                k0[m] = (short)f2bf(a);
                k1[m] = (short)f2bf(b);
                k2[m] = (short)f2bf(c);
            }
            *(short8*)(fb + ((rowb + (256 + u0) * 2) ^ swz)) = dp;
            *(short8*)(fb + ((rowb + (384 + u0) * 2) ^ swz)) = k0;
            *(short8*)(fb + ((rowb + (512 + u0) * 2) ^ swz)) = k1;
            *(short8*)(fb + ((rowb + (640 + u0) * 2) ^ swz)) = k2;
        }
    }
    __syncthreads();   // the ONLY barrier

    const int wave = tid >> 6;
    const int lane = tid & 63;
    const int l15  = lane & 15;
    const int lkb  = (lane >> 4) << 3;
    const int rbase = (lane >> 4) << 2;
    const char* fbr = (const char*)feat;
    const int swzr = (l15 & 7) << 4;

    const unsigned short* WTsg = wt;
    const unsigned short* WTsv = wt + 384 * 384;
    const unsigned short* WTvs = wt + 384 * 384 + 128 * 256;

    float pss[4][4];
    #pragma unroll
    for (int m = 0; m < 4; ++m)
    #pragma unroll
    for (int i = 0; i < 4; ++i) pss[m][i] = psv[(m * 16 + rbase + i) * 4];

    f32x4 accS[3][4];
    #pragma unroll
    for (int t = 0; t < 3; ++t)
    #pragma unroll
    for (int m = 0; m < 4; ++m) accS[t][m] = (f32x4){0,0,0,0};

    #pragma unroll
    for (int ks = 0; ks < 8; ++ks) {
        int kf = ks * 32 + lkb;
        short8 a[4];
        #pragma unroll
        for (int m = 0; m < 4; ++m)
            a[m] = *(const short8*)(fbr + (((m * 16 + l15) * 1536 + kf * 2) ^ swzr));
        #pragma unroll
        for (int t = 0; t < 3; ++t) {
            int ct = wave + t * 8;
            short8 b = *(const short8*)(WTsg + (ct * 16 + l15) * 384 + ks * 32 + lkb);
            #pragma unroll
            for (int m = 0; m < 4; ++m) accS[t][m] = MFMA(a[m], b, accS[t][m]);
        }
    }
    #pragma unroll
    for (int t = 0; t < 3; ++t)
    #pragma unroll
    for (int m = 0; m < 4; ++m)
    #pragma unroll
    for (int i = 0; i < 4; ++i) accS[t][m][i] *= pss[m][i];
    #pragma unroll
    for (int ks = 0; ks < 4; ++ks) {
        int kf = 256 + ks * 32 + lkb;
        short8 a[4];
        #pragma unroll
        for (int m = 0; m < 4; ++m)
            a[m] = *(const short8*)(fbr + (((m * 16 + l15) * 1536 + kf * 2) ^ swzr));
        #pragma unroll
        for (int t = 0; t < 3; ++t) {
            int ct = wave + t * 8;
            short8 b = *(const short8*)(WTsg + (ct * 16 + l15) * 384 + 256 + ks * 32 + lkb);
            #pragma unroll
            for (int m = 0; m < 4; ++m) accS[t][m] = MFMA(a[m], b, accS[t][m]);
        }
    }

    #pragma unroll
    for (int t = 0; t < 2; ++t) {
        int col = (wave + t * 8) * 16 + l15;
        float bc = bias[col];
        #pragma unroll
        for (int m = 0; m < 4; ++m)
        #pragma unroll
        for (int i = 0; i < 4; ++i) {
            int n = n0 + m * 16 + rbase + i;
            if (n < N) {
                float sc = C0F * accS[t][m][i] + bc;
                out[(size_t)n * DIM_Hc + col] = sc / (1.f + __expf(-sc));
            }
        }
    }
    float sgr[4][4];
    #pragma unroll
    for (int m = 0; m < 4; ++m)
    #pragma unroll
    for (int i = 0; i < 4; ++i) sgr[m][i] = 1.f / (1.f + __expf(-C0F * accS[2][m][i]));

    f32x4 accA[4], accV[3][4];
    #pragma unroll
    for (int m = 0; m < 4; ++m) accA[m] = (f32x4){0,0,0,0};
    #pragma unroll
    for (int k = 0; k < 3; ++k)
    #pragma unroll
    for (int m = 0; m < 4; ++m) accV[k][m] = (f32x4){0,0,0,0};

    #pragma unroll
    for (int ks = 0; ks < 8; ++ks) {
        int kf = ks * 32 + lkb;
        short8 b = *(const short8*)(WTsv + (wave * 16 + l15) * 256 + ks * 32 + lkb);
        #pragma unroll
        for (int m = 0; m < 4; ++m) {
            short8 a = *(const short8*)(fbr + (((m * 16 + l15) * 1536 + kf * 2) ^ swzr));
            accA[m] = MFMA(a, b, accA[m]);
        }
    }
    #pragma unroll
    for (int ks = 0; ks < 4; ++ks) {
        short8 b = *(const short8*)(WTvs + (wave * 16 + l15) * 128 + ks * 32 + lkb);
        #pragma unroll
        for (int p = 0; p < 3; ++p) {
            int kf = 384 + 128 * p + ks * 32 + lkb;
            #pragma unroll
            for (int m = 0; m < 4; ++m) {
                short8 a = *(const short8*)(fbr + (((m * 16 + l15) * 1536 + kf * 2) ^ swzr));
                accV[p][m] = MFMA(a, b, accV[p][m]);
            }
        }
    }

    {
        int u = wave * 16 + l15;
        #pragma unroll
        for (int m = 0; m < 4; ++m)
        #pragma unroll
        for (int i = 0; i < 4; ++i) {
            int nl = m * 16 + rbase + i;
            int n = n0 + nl;
            if (n >= N) continue;
            float sg  = sgr[m][i];
            float ps  = pss[m][i];
            float pv0 = psv[nl * 4 + 1], pv1 = psv[nl * 4 + 2], pv2 = psv[nl * 4 + 3];
            float av = accA[m][i];
            size_t ob = (size_t)n * DIM_Hc + MUL_Sc + 3 * u;
            out[ob + 0] = C0F * (av * pv0 + accV[0][m][i] * ps) * sg;
            out[ob + 1] = C0F * (av * pv1 + accV[1][m][i] * ps) * sg;
            out[ob + 2] = C0F * (av * pv2 + accV[2][m][i] * ps) * sg;
        }
    }
}

extern "C" void kernel_launch(void* const* d_in, const int* in_sizes, int n_in,
                              void* d_out, int out_size, void* d_ws, size_t ws_size,
                              hipStream_t stream) {
    const float* din  = (const float*)d_in[0];
    const float* Wss  = (const float*)d_in[1];
    const float* Wvv  = (const float*)d_in[2];
    const float* Wssg = (const float*)d_in[3];
    const float* Wvvg = (const float*)d_in[4];
    const float* Wsv  = (const float*)d_in[5];
    const float* Wvs  = (const float*)d_in[6];
    const float* bias = (const float*)d_in[7];
    float* out = (float*)d_out;
    unsigned short* wt = (unsigned short*)d_ws;

    const size_t WT_SHORTS = 384 * 384 + 128 * 256 + 128 * 128;
    const size_t WT_BYTES = WT_SHORTS * 2;
    if (ws_size < WT_BYTES) return;

    int N = in_sizes[0] / IN_COLS;

    prep_weights<<<((int)WT_SHORTS + 255) / 256, 256, 0, stream>>>(Wss, Wvv, Wssg, Wvvg, Wsv, Wvs, wt);

    // ---- diagnostic: d_out sink (full 256MB, 1 pass) — junk, overwritten below ----
    {
        long long nv4 = (long long)out_size / 4;
        sink_fill<<<2048, 256, 0, stream>>>(out, nv4, 1);
    }
    // ---- diagnostic: d_ws sink (128MB region, 2 passes = 256MB traffic) ----
    {
        size_t avail = ws_size - WT_BYTES;
        size_t region = (size_t)128 * 1024 * 1024;
        if (region > avail) region = avail & ~(size_t)255;
        long long nv4 = (long long)(region / 16);
        float* wsdst = (float*)((char*)d_ws + WT_BYTES);
        if (nv4 > 0) sink_fill<<<2048, 256, 0, stream>>>(wsdst, nv4, 2);
    }

    // ---- real computation (overwrites all of d_out with correct values) ----
    int nblocks = (N + NT - 1) / NT;
    fused_main<<<nblocks, 512, 0, stream>>>(din, wt, bias, out, N);
}